// Round 4
// baseline (258.763 us; speedup 1.0000x reference)
//
#include <hip/hip_runtime.h>
#include <hip/hip_fp16.h>

#define HDIM 256
#define MS 16
#define LDAK 264   // 256 + 8 halves pad
#define CSTRIDE (MS * LDAK * 2)   // 8448 B per channel block

typedef _Float16 half8 __attribute__((ext_vector_type(8)));
typedef _Float16 half4 __attribute__((ext_vector_type(4)));
typedef _Float16 half2v __attribute__((ext_vector_type(2)));
typedef float f32x4 __attribute__((ext_vector_type(4)));

__device__ __forceinline__ float fast_tanh(float x) {
    float e = __expf(2.0f * x);
    return 1.0f - 2.0f * __builtin_amdgcn_rcpf(e + 1.0f);
}

__device__ __forceinline__ half4 cvt4(float a, float b, float c, float d) {
    half2v lo = __builtin_bit_cast(half2v, __builtin_amdgcn_cvt_pkrtz(a, b));
    half2v hi = __builtin_bit_cast(half2v, __builtin_amdgcn_cvt_pkrtz(c, d));
    half4 r; r[0] = lo[0]; r[1] = lo[1]; r[2] = hi[0]; r[3] = hi[1];
    return r;
}

// Barrier draining only LDS (lgkmcnt) — global wf prefetches stay in flight.
__device__ __forceinline__ void barrier_lds() {
    asm volatile("s_waitcnt lgkmcnt(0)\n\ts_barrier" ::: "memory");
}

// Pack W1,W2,W3 (fp32 [256][256]) into f16 frag layout Wp[g*8192 + frag].
__global__ __launch_bounds__(256) void pack_weights(const float* __restrict__ W1,
                                                    const float* __restrict__ W2,
                                                    const float* __restrict__ W3,
                                                    _Float16* __restrict__ out) {
    int tid = blockIdx.x * 256 + threadIdx.x;  // 0..24575
    int l = tid >> 13;
    int idx = tid & 8191;   // kg*256 + n
    int kg = idx >> 8;
    int n = idx & 255;
    const float* W = (l == 0) ? W1 : (l == 1) ? W2 : W3;
    half8 v;
    #pragma unroll
    for (int j = 0; j < 8; ++j) v[j] = (_Float16)W[(kg * 8 + j) * 256 + n];
    *(half8*)(out + l * 65536 + kg * 2048 + n * 8) = v;
}

// Anti-phased two-group pipeline: 512 threads, 8 waves, 32 samples/block,
// 1 block/CU. Waves 0-3 = group A, 4-7 = group B; with round-robin
// wave->SIMD each SIMD hosts one A-wave + one B-wave. Barrier-slotted
// schedule keeps one group in its MFMA K-loop while the other runs its
// VALU elementwise phase, so the HW scheduler feeds the MFMA pipe in
// every slot (no compiler interleave required).
__global__ __launch_bounds__(512, 2)
void pinn_fused(const float* __restrict__ x,
                const float* __restrict__ W0,
                const float* __restrict__ b0,
                const float* __restrict__ b1,
                const float* __restrict__ b2,
                const float* __restrict__ b3,
                const float* __restrict__ Wout,
                const float* __restrict__ bout,
                const _Float16* __restrict__ Wp,
                float* __restrict__ out) {
    __shared__ __align__(16) _Float16 Abuf[2][7 * MS][LDAK];   // per-group jets
    __shared__ float part[2][4 * 7 * MS];                      // per-wave partials

    const int tid  = threadIdx.x;
    const int lane = tid & 63;
    const int wid  = tid >> 6;        // 0..7
    const int grp  = wid >> 2;        // 0: waves 0-3 (A), 1: waves 4-7 (B)
    const int wq   = wid & 3;         // n-strip within group: base wq*64
    const int qd   = lane >> 4;
    const int n15  = lane & 15;
    const int base = blockIdx.x * (2 * MS) + grp * MS;   // this group's samples
    const int nw   = wq * 64 + n15;

    const int voff0 = (qd * 256 + nw) * 8;               // Wp frag base (halves)
    const char* Ab  = (const char*)&Abuf[grp][0][0];
    const int abase = (n15 * LDAK + qd * 8) * 2;         // af read base (bytes)
    char* Sb        = (char*)&Abuf[grp][0][0];
    const int sbase = (n15 * LDAK + wq * 64 + qd * 4) * 2;  // elem write base

    half8 wf[3][4];   // 3-deep rolling W pipeline (per layer)

// Load W frag of (layer L, step S) into wf[BUF]. All indices compile-time.
#define PREFW(L, S, BUF) do { \
    _Pragma("unroll") \
    for (int t_ = 0; t_ < 4; ++t_) \
        wf[BUF][t_] = *(const half8*)(Wp + ((L) * 8 + (S)) * 8192 + voff0 + t_ * 128); \
} while (0)

// Initial 2 frags of layer L (issued in the slot BEFORE that group's K-slot;
// loads stay in flight across the lgkm-only barrier).
#define PREF2(L) do { PREFW(L, 0, 0); PREFW(L, 1, 1); } while (0)

// Load the 7 per-channel A fragments of K-step S into register buffer AF.
#define LDAF(AF, S) do { \
    _Pragma("unroll") \
    for (int c_ = 0; c_ < 7; ++c_) \
        AF[c_] = *(const half8*)(Ab + abase + c_ * CSTRIDE + (S) * 64); \
} while (0)

// 28 MFMAs consuming AF with wf[WB]; setprio favors the K-wave on the CU
// scheduler vs its SIMD-partner wave in the elem phase (true role split).
#define MMS(ACC, AF, WB) do { \
    __builtin_amdgcn_s_setprio(1); \
    _Pragma("unroll") \
    for (int c_ = 0; c_ < 7; ++c_) \
        _Pragma("unroll") \
        for (int t_ = 0; t_ < 4; ++t_) \
            ACC[c_][t_] = __builtin_amdgcn_mfma_f32_16x16x32_f16(wf[WB][t_], AF[c_], ACC[c_][t_], 0, 0, 0); \
    __builtin_amdgcn_s_setprio(0); \
} while (0)

// Software-pipelined 8-step K-loop for layer L: af reg-double-buffered one
// step ahead; wf rolling 3-deep (wf[0],wf[1] preloaded by PREF2(L)).
#define KLOOP(ACC, L) do { \
    half8 afX[7], afY[7]; \
    LDAF(afX, 0); LDAF(afY, 1); \
    PREFW(L, 2, 2); MMS(ACC, afX, 0); LDAF(afX, 2); \
    PREFW(L, 3, 0); MMS(ACC, afY, 1); LDAF(afY, 3); \
    PREFW(L, 4, 1); MMS(ACC, afX, 2); LDAF(afX, 4); \
    PREFW(L, 5, 2); MMS(ACC, afY, 0); LDAF(afY, 5); \
    PREFW(L, 6, 0); MMS(ACC, afX, 1); LDAF(afX, 6); \
    PREFW(L, 7, 1); MMS(ACC, afY, 2); LDAF(afY, 7); \
    MMS(ACC, afX, 0); \
    MMS(ACC, afY, 1); \
} while (0)

#define ZACC(A_) do { \
    _Pragma("unroll") \
    for (int c_ = 0; c_ < 7; ++c_) \
        _Pragma("unroll") \
        for (int t_ = 0; t_ < 4; ++t_) A_[c_][t_] = (f32x4){0.f, 0.f, 0.f, 0.f}; \
} while (0)

// layer 0: this group's 256 threads compute jets for 16 samples x 256 cols.
#define L0G() do { \
    const int m_  = tid & 15; \
    const int nb_ = ((tid & 255) >> 4) * 16; \
    const float x0_ = x[(base + m_) * 3 + 0]; \
    const float x1_ = x[(base + m_) * 3 + 1]; \
    const float x2_ = x[(base + m_) * 3 + 2]; \
    _Pragma("unroll") \
    for (int ch_ = 0; ch_ < 2; ++ch_) { \
        const int n0_ = nb_ + ch_ * 8; \
        f32x4 w0v_[2], w1v_[2], w2v_[2], bv_[2]; \
        w0v_[0] = *(const f32x4*)(W0 + n0_);            w0v_[1] = *(const f32x4*)(W0 + n0_ + 4); \
        w1v_[0] = *(const f32x4*)(W0 + HDIM + n0_);     w1v_[1] = *(const f32x4*)(W0 + HDIM + n0_ + 4); \
        w2v_[0] = *(const f32x4*)(W0 + 2 * HDIM + n0_); w2v_[1] = *(const f32x4*)(W0 + 2 * HDIM + n0_ + 4); \
        bv_[0]  = *(const f32x4*)(b0 + n0_);            bv_[1]  = *(const f32x4*)(b0 + n0_ + 4); \
        half8 h_[7]; \
        _Pragma("unroll") \
        for (int r_ = 0; r_ < 8; ++r_) { \
            const float w0_ = w0v_[r_ >> 2][r_ & 3]; \
            const float w1_ = w1v_[r_ >> 2][r_ & 3]; \
            const float w2_ = w2v_[r_ >> 2][r_ & 3]; \
            float z_  = x0_ * w0_ + x1_ * w1_ + x2_ * w2_ + bv_[r_ >> 2][r_ & 3]; \
            float tv_ = fast_tanh(z_); \
            float dd_ = 1.f - tv_ * tv_; \
            float c2_ = -2.f * tv_ * dd_; \
            h_[0][r_] = (_Float16)tv_; \
            h_[1][r_] = (_Float16)(dd_ * w0_); \
            h_[2][r_] = (_Float16)(dd_ * w1_); \
            h_[3][r_] = (_Float16)(dd_ * w2_); \
            h_[4][r_] = (_Float16)(c2_ * w0_ * w0_); \
            h_[5][r_] = (_Float16)(c2_ * w1_ * w1_); \
            h_[6][r_] = (_Float16)(c2_ * w2_ * w2_); \
        } \
        _Pragma("unroll") \
        for (int c_ = 0; c_ < 7; ++c_) \
            *(half8*)&Abuf[grp][c_ * MS + m_][n0_] = h_[c_]; \
    } \
} while (0)

// lane holds Z[m = n15][n = wq*64 + T*16 + qd*4 + r]; write jets back to LDS.
#define ELEMW(ACC, BB) do { \
    _Pragma("unroll") \
    for (int tt_ = 0; tt_ < 4; ++tt_) { \
        const int ncol_ = wq * 64 + tt_ * 16 + qd * 4; \
        f32x4 bv_ = *(const f32x4*)((BB) + ncol_); \
        float tv_[4], gj_[3][4], sj_[3][4]; \
        _Pragma("unroll") \
        for (int r_ = 0; r_ < 4; ++r_) { \
            float zv_ = ACC[0][tt_][r_] + bv_[r_]; \
            tv_[r_] = fast_tanh(zv_); \
            float dd_ = 1.f - tv_[r_] * tv_[r_]; \
            float c2_ = -2.f * tv_[r_] * dd_; \
            _Pragma("unroll") \
            for (int i_ = 0; i_ < 3; ++i_) { \
                float zg_ = ACC[1 + i_][tt_][r_]; \
                float zs_ = ACC[4 + i_][tt_][r_]; \
                gj_[i_][r_] = dd_ * zg_; \
                sj_[i_][r_] = dd_ * zs_ + c2_ * zg_ * zg_; \
            } \
        } \
        *(half4*)(Sb + sbase + 0 * CSTRIDE + tt_ * 32) = cvt4(tv_[0], tv_[1], tv_[2], tv_[3]); \
        _Pragma("unroll") \
        for (int i_ = 0; i_ < 3; ++i_) { \
            *(half4*)(Sb + sbase + (1 + i_) * CSTRIDE + tt_ * 32) = \
                cvt4(gj_[i_][0], gj_[i_][1], gj_[i_][2], gj_[i_][3]); \
            *(half4*)(Sb + sbase + (4 + i_) * CSTRIDE + tt_ * 32) = \
                cvt4(sj_[i_][0], sj_[i_][1], sj_[i_][2], sj_[i_][3]); \
        } \
    } \
} while (0)

#define OUTG(ACC, G) do { \
    float p_[7] = {0.f, 0.f, 0.f, 0.f, 0.f, 0.f, 0.f}; \
    _Pragma("unroll") \
    for (int tt_ = 0; tt_ < 4; ++tt_) { \
        const int ncol_ = wq * 64 + tt_ * 16 + qd * 4; \
        f32x4 bv_ = *(const f32x4*)(b3 + ncol_); \
        f32x4 wv_ = *(const f32x4*)(Wout + ncol_); \
        _Pragma("unroll") \
        for (int r_ = 0; r_ < 4; ++r_) { \
            float zv_ = ACC[0][tt_][r_] + bv_[r_]; \
            float tv_ = fast_tanh(zv_); \
            float dd_ = 1.f - tv_ * tv_; \
            float c2_ = -2.f * tv_ * dd_; \
            p_[0] += tv_ * wv_[r_]; \
            _Pragma("unroll") \
            for (int i_ = 0; i_ < 3; ++i_) { \
                float zg_ = ACC[1 + i_][tt_][r_]; \
                float zs_ = ACC[4 + i_][tt_][r_]; \
                p_[1 + i_] += (dd_ * zg_) * wv_[r_]; \
                p_[4 + i_] += (dd_ * zs_ + c2_ * zg_ * zg_) * wv_[r_]; \
            } \
        } \
    } \
    _Pragma("unroll") \
    for (int c_ = 0; c_ < 7; ++c_) { \
        p_[c_] += __shfl_xor(p_[c_], 16, 64); \
        p_[c_] += __shfl_xor(p_[c_], 32, 64); \
    } \
    if (lane < 16) { \
        _Pragma("unroll") \
        for (int c_ = 0; c_ < 7; ++c_) \
            part[G][(wq * 7 + c_) * MS + lane] = p_[c_]; \
    } \
} while (0)

    f32x4 acc[7][4];
    PREF2(0);   // both groups: own layer-1 W frags, in flight through slot 0/1

    // slot0: A:L0
    if (grp == 0) { L0G(); }
    barrier_lds();

    // slot1: A:K1  ||  B:L0
    if (grp == 0) { ZACC(acc); KLOOP(acc, 0); }
    else          { L0G(); }
    barrier_lds();

    // slot2: A:elem1 (+prefetch W2)  ||  B:K1
    if (grp == 0) { ELEMW(acc, b1); PREF2(1); }
    else          { ZACC(acc); KLOOP(acc, 0); }
    barrier_lds();

    // slot3: A:K2  ||  B:elem1 (+prefetch W2)
    if (grp == 0) { ZACC(acc); KLOOP(acc, 1); }
    else          { ELEMW(acc, b1); PREF2(1); }
    barrier_lds();

    // slot4: A:elem2 (+prefetch W3)  ||  B:K2
    if (grp == 0) { ELEMW(acc, b2); PREF2(2); }
    else          { ZACC(acc); KLOOP(acc, 1); }
    barrier_lds();

    // slot5: A:K3  ||  B:elem2 (+prefetch W3)
    if (grp == 0) { ZACC(acc); KLOOP(acc, 2); }
    else          { ELEMW(acc, b2); PREF2(2); }
    barrier_lds();

    // slot6: A:out  ||  B:K3 + out   (out touches only regs + part)
    if (grp == 0) { OUTG(acc, 0); }
    else          { ZACC(acc); KLOOP(acc, 2); OUTG(acc, 1); }
    barrier_lds();

    // final reduce across each group's 4 waves; store [B,7] for both groups
    if ((tid & 255) < 112) {
        const int g = tid >> 8;          // 0: tid<112, 1: 256<=tid<368
        const int c = (tid & 255) >> 4;
        const int m = tid & 15;
        float v = part[g][(0 * 7 + c) * MS + m] + part[g][(1 * 7 + c) * MS + m] +
                  part[g][(2 * 7 + c) * MS + m] + part[g][(3 * 7 + c) * MS + m];
        if (c == 0) v += bout[0];
        out[(blockIdx.x * (2 * MS) + g * MS + m) * 7 + c] = v;
    }

#undef PREFW
#undef PREF2
#undef LDAF
#undef MMS
#undef KLOOP
#undef ZACC
#undef L0G
#undef ELEMW
#undef OUTG
}

extern "C" void kernel_launch(void* const* d_in, const int* in_sizes, int n_in,
                              void* d_out, int out_size, void* d_ws, size_t ws_size,
                              hipStream_t stream) {
    const float* xp   = (const float*)d_in[0];
    const float* W0   = (const float*)d_in[1];
    const float* b0   = (const float*)d_in[2];
    const float* W1   = (const float*)d_in[3];
    const float* b1   = (const float*)d_in[4];
    const float* W2   = (const float*)d_in[5];
    const float* b2   = (const float*)d_in[6];
    const float* W3   = (const float*)d_in[7];
    const float* b3   = (const float*)d_in[8];
    const float* Wout = (const float*)d_in[9];
    const float* bout = (const float*)d_in[10];
    _Float16* Wp = (_Float16*)d_ws;  // 3 * 65536 halves = 384 KB

    pack_weights<<<96, 256, 0, stream>>>(W1, W2, W3, Wp);
    pinn_fused<<<65536 / (2 * MS), 512, 0, stream>>>(xp, W0, b0, b1, b2, b3, Wout, bout,
                                                     Wp, (float*)d_out);
}

// Round 5
// 242.304 us; speedup vs baseline: 1.0679x; 1.0679x over previous
//
#include <hip/hip_runtime.h>
#include <hip/hip_fp16.h>

#define HDIM 256
#define MS 16
#define LDAK 264   // 256 + 8 halves pad; measured-balanced for b128 reads & b64 writes
#define CSTRIDE (MS * LDAK * 2)   // 8448 B per channel block

typedef _Float16 half8 __attribute__((ext_vector_type(8)));
typedef _Float16 half4 __attribute__((ext_vector_type(4)));
typedef _Float16 half2v __attribute__((ext_vector_type(2)));
typedef float f32x4 __attribute__((ext_vector_type(4)));

__device__ __forceinline__ float fast_tanh(float x) {
    // tanh(x) = 1 - 2/(e^{2x}+1); v_exp-based, graceful at +-inf
    float e = __expf(2.0f * x);
    return 1.0f - 2.0f * __builtin_amdgcn_rcpf(e + 1.0f);
}

__device__ __forceinline__ half4 cvt4(float a, float b, float c, float d) {
    half2v lo = __builtin_bit_cast(half2v, __builtin_amdgcn_cvt_pkrtz(a, b));
    half2v hi = __builtin_bit_cast(half2v, __builtin_amdgcn_cvt_pkrtz(c, d));
    half4 r; r[0] = lo[0]; r[1] = lo[1]; r[2] = hi[0]; r[3] = hi[1];
    return r;
}

// Workgroup barrier draining only LDS (lgkmcnt) — leaves in-flight global
// wf prefetches (vmcnt) pending across the barrier.
__device__ __forceinline__ void barrier_lds() {
    asm volatile("s_waitcnt lgkmcnt(0)\n\ts_barrier" ::: "memory");
}

// Pack W1,W2,W3 (fp32 [256][256]) into f16 frag layout Wp[g*8192 + frag], g = flat
// K-step l*8+s; within a step: kg-sub*2048 + n*8 + (k&7).
__global__ __launch_bounds__(256) void pack_weights(const float* __restrict__ W1,
                                                    const float* __restrict__ W2,
                                                    const float* __restrict__ W3,
                                                    _Float16* __restrict__ out) {
    int tid = blockIdx.x * 256 + threadIdx.x;  // 0..24575
    int l = tid >> 13;
    int idx = tid & 8191;   // kg*256 + n
    int kg = idx >> 8;      // k-group of 8
    int n = idx & 255;
    const float* W = (l == 0) ? W1 : (l == 1) ? W2 : W3;
    half8 v;
    #pragma unroll
    for (int j = 0; j < 8; ++j) v[j] = (_Float16)W[(kg * 8 + j) * 256 + n];
    *(half8*)(out + l * 65536 + kg * 2048 + n * 8) = v;
}

__global__ __launch_bounds__(256, 2)
void pinn_fused(const float* __restrict__ x,
                const float* __restrict__ W0,
                const float* __restrict__ b0,
                const float* __restrict__ b1,
                const float* __restrict__ b2,
                const float* __restrict__ b3,
                const float* __restrict__ Wout,
                const float* __restrict__ bout,
                const _Float16* __restrict__ Wp,
                float* __restrict__ out) {
    // A: stacked [7 channels x 16 samples] rows x 256 k, f16, pad-264
    __shared__ __align__(16) _Float16 Abuf[7 * MS][LDAK];
    __shared__ float part[4 * 7 * MS];   // per-wave output partials (1792 B)

    const int tid  = threadIdx.x;
    const int lane = tid & 63;
    const int wid  = tid >> 6;        // wave 0..3 -> n-strip base wid*64
    const int qd   = lane >> 4;
    const int n15  = lane & 15;
    const int base = blockIdx.x * MS;
    const int nw   = wid * 64 + n15;

    // Linear W addressing: frag(g,t) at Wbase + g*8192 + t*128 (halves).
    const _Float16* Wbase = Wp + (qd * 256 + nw) * 8;

    const char* Ab = (const char*)Abuf;
    const int abase = (n15 * LDAK + qd * 8) * 2;                 // read base (bytes)
    char* Sb = (char*)Abuf;
    const int sbase = (n15 * LDAK + wid * 64 + qd * 4) * 2;      // write base (bytes)

    // 2-deep ping-pong W-fragment pipeline over flat step g = l*8 + s.
    // (3-deep spilled the pipeline: 112 AGPR acc + 56 af + 48 wf + temps > 256
    //  per-wave budget at 2 waves/SIMD, and the allocator collapsed the
    //  prefetches down to their uses. 2-deep = 32 regs fits; one step of MFMA
    //  issue (~540cy) still covers L2-hit latency (~200cy).)
    half8 wf[2][4];

#define PREF(G) do { \
    if ((G) < 24) { \
        _Pragma("unroll") \
        for (int t_ = 0; t_ < 4; ++t_) \
            wf[(G) & 1][t_] = *(const half8*)(Wbase + (G) * 8192 + t_ * 128); \
    } \
} while (0)

// Load the 7 per-channel A fragments of K-step S into register buffer AF.
#define LDAF(AF, S) do { \
    _Pragma("unroll") \
    for (int c_ = 0; c_ < 7; ++c_) \
        AF[c_] = *(const half8*)(Ab + abase + c_ * CSTRIDE + (S) * 64); \
} while (0)

// 28 MFMAs of flat step G consuming AF (loaded one step earlier), plus
// wf prefetch for G+1 (consumed one step later). setprio keeps the MFMA
// wave favored vs the co-resident block's memory-phase waves.
#define MMS(ACC, AF, G) do { \
    PREF((G) + 1); \
    __builtin_amdgcn_s_setprio(1); \
    _Pragma("unroll") \
    for (int c_ = 0; c_ < 7; ++c_) \
        _Pragma("unroll") \
        for (int t_ = 0; t_ < 4; ++t_) \
            ACC[c_][t_] = __builtin_amdgcn_mfma_f32_16x16x32_f16(wf[(G) & 1][t_], AF[c_], ACC[c_][t_], 0, 0, 0); \
    __builtin_amdgcn_s_setprio(0); \
} while (0)

// Software-pipelined 8-step K-loop: af double-buffered in registers, each
// LDAF issued one step ahead of its consuming MFMA cluster so LDS latency
// hides under ~540cy of MFMA issue. G0 = 8*layer.
#define KLOOP(ACC, G0) do { \
    half8 afX[7], afY[7]; \
    LDAF(afX, 0); \
    LDAF(afY, 1); \
    MMS(ACC, afX, (G0) + 0); \
    LDAF(afX, 2); \
    MMS(ACC, afY, (G0) + 1); \
    LDAF(afY, 3); \
    MMS(ACC, afX, (G0) + 2); \
    LDAF(afX, 4); \
    MMS(ACC, afY, (G0) + 3); \
    LDAF(afY, 5); \
    MMS(ACC, afX, (G0) + 4); \
    LDAF(afX, 6); \
    MMS(ACC, afY, (G0) + 5); \
    LDAF(afY, 7); \
    MMS(ACC, afX, (G0) + 6); \
    MMS(ACC, afY, (G0) + 7); \
} while (0)

#define ZACC(A_) do { \
    _Pragma("unroll") \
    for (int c_ = 0; c_ < 7; ++c_) \
        _Pragma("unroll") \
        for (int t_ = 0; t_ < 4; ++t_) A_[c_][t_] = (f32x4){0.f, 0.f, 0.f, 0.f}; \
} while (0)

    // initial W prefetch: g=0 (g=1 is fetched inside MMS(...,0))
    PREF(0);

    // ---------------- layer 0: 3 -> 256, jets analytic; vectorized loads ----------------
    {
        const int m  = tid & 15;
        const int nb = (tid >> 4) * 16;   // 16 consecutive n per thread, 2 chunks
        const float x0 = x[(base + m) * 3 + 0];
        const float x1 = x[(base + m) * 3 + 1];
        const float x2 = x[(base + m) * 3 + 2];
        #pragma unroll
        for (int ch = 0; ch < 2; ++ch) {
            const int n0 = nb + ch * 8;
            f32x4 w0v[2], w1v[2], w2v[2], bv[2];
            w0v[0] = *(const f32x4*)(W0 + n0);            w0v[1] = *(const f32x4*)(W0 + n0 + 4);
            w1v[0] = *(const f32x4*)(W0 + HDIM + n0);     w1v[1] = *(const f32x4*)(W0 + HDIM + n0 + 4);
            w2v[0] = *(const f32x4*)(W0 + 2 * HDIM + n0); w2v[1] = *(const f32x4*)(W0 + 2 * HDIM + n0 + 4);
            bv[0]  = *(const f32x4*)(b0 + n0);            bv[1]  = *(const f32x4*)(b0 + n0 + 4);
            half8 h[7];
            #pragma unroll
            for (int r = 0; r < 8; ++r) {
                const float w0 = w0v[r >> 2][r & 3];
                const float w1 = w1v[r >> 2][r & 3];
                const float w2 = w2v[r >> 2][r & 3];
                float z  = x0 * w0 + x1 * w1 + x2 * w2 + bv[r >> 2][r & 3];
                float tv = fast_tanh(z);
                float dd = 1.f - tv * tv;
                float c2 = -2.f * tv * dd;
                h[0][r] = (_Float16)tv;
                h[1][r] = (_Float16)(dd * w0);
                h[2][r] = (_Float16)(dd * w1);
                h[3][r] = (_Float16)(dd * w2);
                h[4][r] = (_Float16)(c2 * w0 * w0);
                h[5][r] = (_Float16)(c2 * w1 * w1);
                h[6][r] = (_Float16)(c2 * w2 * w2);
            }
            #pragma unroll
            for (int c = 0; c < 7; ++c)
                *(half8*)&Abuf[c * MS + m][n0] = h[c];
        }
    }
    barrier_lds();

    // ---------------- layers 1..2: pipelined MFMA + elem write-back ----------------
    #pragma unroll
    for (int l = 0; l < 2; ++l) {
        const float* bb = (l == 0) ? b1 : b2;

        f32x4 acc[7][4];
        ZACC(acc);
        KLOOP(acc, l * 8);
        barrier_lds();   // all waves done reading Abuf (lgkm only; wf stays in flight)

        // lane holds Z[m = n15][n = wid*64 + t*16 + qd*4 + r], r=0..3
        #pragma unroll
        for (int t = 0; t < 4; ++t) {
            const int ncol = wid * 64 + t * 16 + qd * 4;
            f32x4 bv = *(const f32x4*)(bb + ncol);
            float tv[4], gj[3][4], sj[3][4];
            #pragma unroll
            for (int r = 0; r < 4; ++r) {
                float zv = acc[0][t][r] + bv[r];
                tv[r] = fast_tanh(zv);
                float dd = 1.f - tv[r] * tv[r];
                float c2 = -2.f * tv[r] * dd;
                #pragma unroll
                for (int i = 0; i < 3; ++i) {
                    float zg = acc[1 + i][t][r];
                    float zs = acc[4 + i][t][r];
                    gj[i][r] = dd * zg;
                    sj[i][r] = dd * zs + c2 * zg * zg;
                }
            }
            *(half4*)(Sb + sbase + 0 * CSTRIDE + t * 32) = cvt4(tv[0], tv[1], tv[2], tv[3]);
            #pragma unroll
            for (int i = 0; i < 3; ++i) {
                *(half4*)(Sb + sbase + (1 + i) * CSTRIDE + t * 32) =
                    cvt4(gj[i][0], gj[i][1], gj[i][2], gj[i][3]);
                *(half4*)(Sb + sbase + (4 + i) * CSTRIDE + t * 32) =
                    cvt4(sj[i][0], sj[i][1], sj[i][2], sj[i][3]);
            }
        }
        barrier_lds();   // writes visible before next K
    }

    // ---------------- layer 3: K-loop + FUSED elem/output (no Abuf writes) ----------------
    {
        f32x4 acc[7][4];
        ZACC(acc);
        KLOOP(acc, 16);
        // No post-K barrier: fused elem touches only registers + `part`.

        // per-lane partial dot with Wout over this lane's 16 columns (fp32 path)
        float p[7] = {0.f, 0.f, 0.f, 0.f, 0.f, 0.f, 0.f};
        #pragma unroll
        for (int t = 0; t < 4; ++t) {
            const int ncol = wid * 64 + t * 16 + qd * 4;
            f32x4 bv = *(const f32x4*)(b3 + ncol);
            f32x4 wv = *(const f32x4*)(Wout + ncol);
            #pragma unroll
            for (int r = 0; r < 4; ++r) {
                float zv = acc[0][t][r] + bv[r];
                float tv = fast_tanh(zv);
                float dd = 1.f - tv * tv;
                float c2 = -2.f * tv * dd;
                p[0] += tv * wv[r];
                #pragma unroll
                for (int i = 0; i < 3; ++i) {
                    float zg = acc[1 + i][t][r];
                    float zs = acc[4 + i][t][r];
                    p[1 + i] += (dd * zg) * wv[r];
                    p[4 + i] += (dd * zs + c2 * zg * zg) * wv[r];
                }
            }
        }
        // reduce over the 4 qd lanes sharing sample n15
        #pragma unroll
        for (int c = 0; c < 7; ++c) {
            p[c] += __shfl_xor(p[c], 16, 64);
            p[c] += __shfl_xor(p[c], 32, 64);
        }
        if (lane < 16) {
            #pragma unroll
            for (int c = 0; c < 7; ++c)
                part[(wid * 7 + c) * MS + lane] = p[c];
        }
    }
    barrier_lds();

    // ---------------- final reduce across the 4 waves; store [B,7] ----------------
    if (tid < 7 * MS) {
        const int c = tid >> 4;   // channel
        const int m = tid & 15;   // sample
        float v = part[(0 * 7 + c) * MS + m] + part[(1 * 7 + c) * MS + m] +
                  part[(2 * 7 + c) * MS + m] + part[(3 * 7 + c) * MS + m];
        if (c == 0) v += bout[0];
        out[(base + m) * 7 + c] = v;
    }

#undef PREF
#undef LDAF
#undef MMS
#undef KLOOP
#undef ZACC
}

extern "C" void kernel_launch(void* const* d_in, const int* in_sizes, int n_in,
                              void* d_out, int out_size, void* d_ws, size_t ws_size,
                              hipStream_t stream) {
    const float* xp   = (const float*)d_in[0];
    const float* W0   = (const float*)d_in[1];
    const float* b0   = (const float*)d_in[2];
    const float* W1   = (const float*)d_in[3];
    const float* b1   = (const float*)d_in[4];
    const float* W2   = (const float*)d_in[5];
    const float* b2   = (const float*)d_in[6];
    const float* W3   = (const float*)d_in[7];
    const float* b3   = (const float*)d_in[8];
    const float* Wout = (const float*)d_in[9];
    const float* bout = (const float*)d_in[10];
    _Float16* Wp = (_Float16*)d_ws;  // 3 * 65536 halves = 384 KB

    pack_weights<<<96, 256, 0, stream>>>(W1, W2, W3, Wp);
    pinn_fused<<<65536 / MS, 256, 0, stream>>>(xp, W0, b0, b1, b2, b3, Wout, bout, Wp,
                                               (float*)d_out);
}

// Round 7
// 241.001 us; speedup vs baseline: 1.0737x; 1.0054x over previous
//
#include <hip/hip_runtime.h>
#include <hip/hip_fp16.h>

#define HDIM 256
#define MS 16
#define LDAK 264   // 256 + 8 halves pad; measured-balanced for b128 reads & b64 writes
#define CSTRIDE (MS * LDAK * 2)   // 8448 B per channel block

typedef _Float16 half8 __attribute__((ext_vector_type(8)));
typedef _Float16 half4 __attribute__((ext_vector_type(4)));
typedef _Float16 half2v __attribute__((ext_vector_type(2)));
typedef float f32x4 __attribute__((ext_vector_type(4)));

__device__ __forceinline__ float fast_tanh(float x) {
    // tanh(x) = 1 - 2/(e^{2x}+1); v_exp-based, graceful at +-inf
    float e = __expf(2.0f * x);
    return 1.0f - 2.0f * __builtin_amdgcn_rcpf(e + 1.0f);
}

__device__ __forceinline__ half4 cvt4(float a, float b, float c, float d) {
    half2v lo = __builtin_bit_cast(half2v, __builtin_amdgcn_cvt_pkrtz(a, b));
    half2v hi = __builtin_bit_cast(half2v, __builtin_amdgcn_cvt_pkrtz(c, d));
    half4 r; r[0] = lo[0]; r[1] = lo[1]; r[2] = hi[0]; r[3] = hi[1];
    return r;
}

// Workgroup barrier draining only LDS (lgkmcnt) — leaves in-flight global
// wf prefetches (vmcnt) pending across the barrier.
__device__ __forceinline__ void barrier_lds() {
    asm volatile("s_waitcnt lgkmcnt(0)\n\ts_barrier" ::: "memory");
}

// Pack W1,W2,W3 (fp32 [256][256]) into f16 frag layout Wp[g*8192 + frag], g = flat
// K-step l*8+s; within a step: kg-sub*2048 + n*8 + (k&7).
__global__ __launch_bounds__(256) void pack_weights(const float* __restrict__ W1,
                                                    const float* __restrict__ W2,
                                                    const float* __restrict__ W3,
                                                    _Float16* __restrict__ out) {
    int tid = blockIdx.x * 256 + threadIdx.x;  // 0..24575
    int l = tid >> 13;
    int idx = tid & 8191;   // kg*256 + n
    int kg = idx >> 8;      // k-group of 8
    int n = idx & 255;
    const float* W = (l == 0) ? W1 : (l == 1) ? W2 : W3;
    half8 v;
    #pragma unroll
    for (int j = 0; j < 8; ++j) v[j] = (_Float16)W[(kg * 8 + j) * 256 + n];
    *(half8*)(out + l * 65536 + kg * 2048 + n * 8) = v;
}

// Region-ownership rotated schedule: wave w's elem writes cols [64w,64w+64),
// which is exactly the k-range of next-layer K-steps {2w, 2w+1}. Rotating
// each wave's K order to start at s=2*wid lets 2 K-steps run BEFORE the
// layer barrier (own-region only, within-wave LDS RAW is pipe-ordered),
// and splitting elem into reg-compute / LDS-store moves the tanh/jet VALU
// before the post-K barrier. Every barrier gets slack work in front.
__global__ __launch_bounds__(256, 2)
void pinn_fused(const float* __restrict__ x,
                const float* __restrict__ W0,
                const float* __restrict__ b0,
                const float* __restrict__ b1,
                const float* __restrict__ b2,
                const float* __restrict__ b3,
                const float* __restrict__ Wout,
                const float* __restrict__ bout,
                const _Float16* __restrict__ Wp,
                float* __restrict__ out) {
    // A: stacked [7 channels x 16 samples] rows x 256 k, f16, pad-264
    __shared__ __align__(16) _Float16 Abuf[7 * MS][LDAK];
    __shared__ float part[4 * 7 * MS];   // per-wave output partials (1792 B)

    const int tid  = threadIdx.x;
    const int lane = tid & 63;
    const int wid  = tid >> 6;        // wave 0..3 -> n-strip base wid*64
    const int qd   = lane >> 4;
    const int n15  = lane & 15;
    const int base = blockIdx.x * MS;
    const int nw   = wid * 64 + n15;
    const int rot  = wid * 2;         // wave-owned k-step rotation

    // Linear W addressing: frag(g,t) at Wbase + g*8192 + t*128 (halves).
    const _Float16* Wbase = Wp + (qd * 256 + nw) * 8;

    const char* Ab = (const char*)Abuf;
    const int abase = (n15 * LDAK + qd * 8) * 2;                 // read base (bytes)
    char* Sb = (char*)Abuf;
    const int sbase = (n15 * LDAK + wid * 64 + qd * 4) * 2;      // write base (bytes)

    // 2-deep ping-pong W-fragment pipeline over flat position jj = l*8 + i;
    // actual k-step s = (rot + i) & 7 (per-wave rotated), g = l*8 + s.
    half8 wf[2][4];

#define PREFJ(JJ) do { \
    if ((JJ) < 24) { \
        const int g_ = (((JJ) >> 3) * 8 + ((rot + ((JJ) & 7)) & 7)); \
        _Pragma("unroll") \
        for (int t_ = 0; t_ < 4; ++t_) \
            wf[(JJ) & 1][t_] = *(const half8*)(Wbase + g_ * 8192 + t_ * 128); \
    } \
} while (0)

// Load the 7 per-channel A fragments of rotated position I into AF.
#define LDAFS(AF, I) do { \
    const int so_ = ((rot + (I)) & 7) * 64; \
    _Pragma("unroll") \
    for (int c_ = 0; c_ < 7; ++c_) \
        AF[c_] = *(const half8*)(Ab + abase + c_ * CSTRIDE + so_); \
} while (0)

// 28 MFMAs at position JJ consuming AF; prefetch wf for JJ+1.
#define MMSJ(ACC, AF, JJ) do { \
    PREFJ((JJ) + 1); \
    __builtin_amdgcn_s_setprio(1); \
    _Pragma("unroll") \
    for (int c_ = 0; c_ < 7; ++c_) \
        _Pragma("unroll") \
        for (int t_ = 0; t_ < 4; ++t_) \
            ACC[c_][t_] = __builtin_amdgcn_mfma_f32_16x16x32_f16(wf[(JJ) & 1][t_], AF[c_], ACC[c_][t_], 0, 0, 0); \
    __builtin_amdgcn_s_setprio(0); \
} while (0)

// PRE: positions 0,1 of layer L = steps {2w, 2w+1} reading ONLY this wave's
// own freshly-written region -> legal before the layer barrier.
#define KPRE(ACC, L) do { \
    half8 afX[7], afY[7]; \
    LDAFS(afX, 0); LDAFS(afY, 1); \
    MMSJ(ACC, afX, (L) * 8 + 0); \
    MMSJ(ACC, afY, (L) * 8 + 1); \
} while (0)

// POST: positions 2..7 (other waves' regions) after the barrier; af
// register-double-buffered one step ahead.
#define KPOST(ACC, L) do { \
    half8 afX[7], afY[7]; \
    LDAFS(afX, 2); LDAFS(afY, 3); \
    MMSJ(ACC, afX, (L) * 8 + 2); LDAFS(afX, 4); \
    MMSJ(ACC, afY, (L) * 8 + 3); LDAFS(afY, 5); \
    MMSJ(ACC, afX, (L) * 8 + 4); LDAFS(afX, 6); \
    MMSJ(ACC, afY, (L) * 8 + 5); LDAFS(afY, 7); \
    MMSJ(ACC, afX, (L) * 8 + 6); \
    MMSJ(ACC, afY, (L) * 8 + 7); \
} while (0)

#define ZACC(A_) do { \
    _Pragma("unroll") \
    for (int c_ = 0; c_ < 7; ++c_) \
        _Pragma("unroll") \
        for (int t_ = 0; t_ < 4; ++t_) A_[c_][t_] = (f32x4){0.f, 0.f, 0.f, 0.f}; \
} while (0)

// elem compute (REGISTERS ONLY — runs before the post-K barrier):
// lane holds Z[m = n15][n = wid*64 + tt*16 + qd*4 + r], r=0..3
#define ELEMC(ACC, BB, EV) do { \
    _Pragma("unroll") \
    for (int tt_ = 0; tt_ < 4; ++tt_) { \
        const int ncol_ = wid * 64 + tt_ * 16 + qd * 4; \
        f32x4 bv_ = *(const f32x4*)((BB) + ncol_); \
        float tv_[4], gj_[3][4], sj_[3][4]; \
        _Pragma("unroll") \
        for (int r_ = 0; r_ < 4; ++r_) { \
            float zv_ = ACC[0][tt_][r_] + bv_[r_]; \
            tv_[r_] = fast_tanh(zv_); \
            float dd_ = 1.f - tv_[r_] * tv_[r_]; \
            float c2_ = -2.f * tv_[r_] * dd_; \
            _Pragma("unroll") \
            for (int i_ = 0; i_ < 3; ++i_) { \
                float zg_ = ACC[1 + i_][tt_][r_]; \
                float zs_ = ACC[4 + i_][tt_][r_]; \
                gj_[i_][r_] = dd_ * zg_; \
                sj_[i_][r_] = dd_ * zs_ + c2_ * zg_ * zg_; \
            } \
        } \
        EV[0][tt_] = cvt4(tv_[0], tv_[1], tv_[2], tv_[3]); \
        _Pragma("unroll") \
        for (int i_ = 0; i_ < 3; ++i_) { \
            EV[1 + i_][tt_] = cvt4(gj_[i_][0], gj_[i_][1], gj_[i_][2], gj_[i_][3]); \
            EV[4 + i_][tt_] = cvt4(sj_[i_][0], sj_[i_][1], sj_[i_][2], sj_[i_][3]); \
        } \
    } \
} while (0)

// elem store (after the barrier; 28 cheap ds_writes to this wave's region)
#define ELEMS(EV) do { \
    _Pragma("unroll") \
    for (int c_ = 0; c_ < 7; ++c_) \
        _Pragma("unroll") \
        for (int tt_ = 0; tt_ < 4; ++tt_) \
            *(half4*)(Sb + sbase + c_ * CSTRIDE + tt_ * 32) = EV[c_][tt_]; \
} while (0)

    f32x4 acc[7][4];
    half4 ev[7][4];

    ZACC(acc);
    PREFJ(0);

    // ---------------- layer 0: 3 -> 256, jets analytic; writes OWN region ----------------
    {
        const int m  = tid & 15;
        const int nb = (tid >> 4) * 16;   // wave w's threads cover cols [64w,64w+64)
        const float x0 = x[(base + m) * 3 + 0];
        const float x1 = x[(base + m) * 3 + 1];
        const float x2 = x[(base + m) * 3 + 2];
        #pragma unroll
        for (int ch = 0; ch < 2; ++ch) {
            const int n0 = nb + ch * 8;
            f32x4 w0v[2], w1v[2], w2v[2], bv[2];
            w0v[0] = *(const f32x4*)(W0 + n0);            w0v[1] = *(const f32x4*)(W0 + n0 + 4);
            w1v[0] = *(const f32x4*)(W0 + HDIM + n0);     w1v[1] = *(const f32x4*)(W0 + HDIM + n0 + 4);
            w2v[0] = *(const f32x4*)(W0 + 2 * HDIM + n0); w2v[1] = *(const f32x4*)(W0 + 2 * HDIM + n0 + 4);
            bv[0]  = *(const f32x4*)(b0 + n0);            bv[1]  = *(const f32x4*)(b0 + n0 + 4);
            half8 h[7];
            #pragma unroll
            for (int r = 0; r < 8; ++r) {
                const float w0 = w0v[r >> 2][r & 3];
                const float w1 = w1v[r >> 2][r & 3];
                const float w2 = w2v[r >> 2][r & 3];
                float z  = x0 * w0 + x1 * w1 + x2 * w2 + bv[r >> 2][r & 3];
                float tv = fast_tanh(z);
                float dd = 1.f - tv * tv;
                float c2 = -2.f * tv * dd;
                h[0][r] = (_Float16)tv;
                h[1][r] = (_Float16)(dd * w0);
                h[2][r] = (_Float16)(dd * w1);
                h[3][r] = (_Float16)(dd * w2);
                h[4][r] = (_Float16)(c2 * w0 * w0);
                h[5][r] = (_Float16)(c2 * w1 * w1);
                h[6][r] = (_Float16)(c2 * w2 * w2);
            }
            #pragma unroll
            for (int c = 0; c < 7; ++c)
                *(half8*)&Abuf[c * MS + m][n0] = h[c];
        }
    }
    // K1 pre-steps on own region (no barrier yet; same-wave LDS pipe ordering)
    KPRE(acc, 0);
    barrier_lds();          // B2(0)

    // ---------------- layer 1 ----------------
    KPOST(acc, 0);
    ELEMC(acc, b1, ev);     // register-only; pads B1(1)
    barrier_lds();          // B1(1): all waves done reading layer-1 Abuf
    ELEMS(ev);
    ZACC(acc);
    KPRE(acc, 1);           // own-region steps of layer 2; pads B2(1)
    barrier_lds();          // B2(1)

    // ---------------- layer 2 ----------------
    KPOST(acc, 1);
    ELEMC(acc, b2, ev);
    barrier_lds();          // B1(2)
    ELEMS(ev);
    ZACC(acc);
    KPRE(acc, 2);
    barrier_lds();          // B2(2)

    // ---------------- layer 3: K POST + FUSED output ----------------
    KPOST(acc, 2);
    {
        // per-lane partial dot with Wout over this lane's 16 columns (fp32 path)
        float p[7] = {0.f, 0.f, 0.f, 0.f, 0.f, 0.f, 0.f};
        #pragma unroll
        for (int t = 0; t < 4; ++t) {
            const int ncol = wid * 64 + t * 16 + qd * 4;
            f32x4 bv = *(const f32x4*)(b3 + ncol);
            f32x4 wv = *(const f32x4*)(Wout + ncol);
            #pragma unroll
            for (int r = 0; r < 4; ++r) {
                float zv = acc[0][t][r] + bv[r];
                float tv = fast_tanh(zv);
                float dd = 1.f - tv * tv;
                float c2 = -2.f * tv * dd;
                p[0] += tv * wv[r];
                #pragma unroll
                for (int i = 0; i < 3; ++i) {
                    float zg = acc[1 + i][t][r];
                    float zs = acc[4 + i][t][r];
                    p[1 + i] += (dd * zg) * wv[r];
                    p[4 + i] += (dd * zs + c2 * zg * zg) * wv[r];
                }
            }
        }
        // reduce over the 4 qd lanes sharing sample n15
        #pragma unroll
        for (int c = 0; c < 7; ++c) {
            p[c] += __shfl_xor(p[c], 16, 64);
            p[c] += __shfl_xor(p[c], 32, 64);
        }
        if (lane < 16) {
            #pragma unroll
            for (int c = 0; c < 7; ++c)
                part[(wid * 7 + c) * MS + lane] = p[c];
        }
    }
    barrier_lds();

    // ---------------- final reduce across the 4 waves; store [B,7] ----------------
    if (tid < 7 * MS) {
        const int c = tid >> 4;   // channel
        const int m = tid & 15;   // sample
        float v = part[(0 * 7 + c) * MS + m] + part[(1 * 7 + c) * MS + m] +
                  part[(2 * 7 + c) * MS + m] + part[(3 * 7 + c) * MS + m];
        if (c == 0) v += bout[0];
        out[(base + m) * 7 + c] = v;
    }

#undef PREFJ
#undef LDAFS
#undef MMSJ
#undef KPRE
#undef KPOST
#undef ZACC
#undef ELEMC
#undef ELEMS
}

extern "C" void kernel_launch(void* const* d_in, const int* in_sizes, int n_in,
                              void* d_out, int out_size, void* d_ws, size_t ws_size,
                              hipStream_t stream) {
    const float* xp   = (const float*)d_in[0];
    const float* W0   = (const float*)d_in[1];
    const float* b0   = (const float*)d_in[2];
    const float* W1   = (const float*)d_in[3];
    const float* b1   = (const float*)d_in[4];
    const float* W2   = (const float*)d_in[5];
    const float* b2   = (const float*)d_in[6];
    const float* W3   = (const float*)d_in[7];
    const float* b3   = (const float*)d_in[8];
    const float* Wout = (const float*)d_in[9];
    const float* bout = (const float*)d_in[10];
    _Float16* Wp = (_Float16*)d_ws;  // 3 * 65536 halves = 384 KB

    pack_weights<<<96, 256, 0, stream>>>(W1, W2, W3, Wp);
    pinn_fused<<<65536 / MS, 256, 0, stream>>>(xp, W0, b0, b1, b2, b3, Wout, bout, Wp,
                                               (float*)d_out);
}